// Round 11
// baseline (247.453 us; speedup 1.0000x reference)
//
#include <hip/hip_runtime.h>
#include <hip/hip_fp8.h>
#include <math.h>

#define BSZ   8192
#define NCLS  57
#define DIM   256
#define NTASK 57
#define INV_T (1.0f/0.07f)
#define GBM   64                 // row tiles (128 rows each)
#define GBN   32                 // col tiles (256 cols each)
#define FIN_GRID 32

typedef float f32x4 __attribute__((ext_vector_type(4)));
typedef long  lgx2  __attribute__((ext_vector_type(2)));

// async global->LDS, 16B per lane; l must be wave-uniform base (HW adds lane*16)
__device__ __forceinline__ void gload_lds16(const void* g, void* l) {
    __builtin_amdgcn_global_load_lds(
        (const __attribute__((address_space(1))) unsigned int*)g,
        (__attribute__((address_space(3))) unsigned int*)l, 16, 0, 0);
}

__device__ __forceinline__ void decode_block(int& bm, int& bn) {
    int b = (blockIdx.x & 7) * (2048 / 8) + (blockIdx.x >> 3);   // XCD swizzle
    bm = b >> 5; bn = b & 31;
}

// ---- kernel 1: fused logits stats + normalize->fp8 (K-interleaved) -----------------
__global__ __launch_bounds__(256) void k_prep(
        const float* __restrict__ logits, const float* __restrict__ emb,
        const int* __restrict__ labels, const int* __restrict__ tasks,
        float* __restrict__ u, float* __restrict__ cls_part,
        int* __restrict__ task_count, unsigned char* __restrict__ e) {
    __shared__ float scls[4];
    int wave = threadIdx.x >> 6;
    int lane = threadIdx.x & 63;
    int row  = blockIdx.x * 4 + wave;

    float v = (lane < NCLS) ? logits[row * NCLS + lane] : -3.0e38f;
    float m = v;
    #pragma unroll
    for (int s = 1; s < 64; s <<= 1) m = fmaxf(m, __shfl_xor(m, s));
    float ex = (lane < NCLS) ? __expf(v - m) : 0.0f;
    float se = ex;
    #pragma unroll
    for (int s = 1; s < 64; s <<= 1) se += __shfl_xor(se, s);
    float lse = m + logf(se);
    float p = ex / se;
    float term = (lane < NCLS) ? p * logf(p + 1e-8f) : 0.0f;
    float ent = term;
    #pragma unroll
    for (int s = 1; s < 64; s <<= 1) ent += __shfl_xor(ent, s);
    ent = -ent;
    int lab = labels[row];
    float vl = __shfl(v, lab);
    float cls = lse - vl;

    const float4* src = reinterpret_cast<const float4*>(emb + (size_t)row * DIM);
    float4 x = src[lane];
    float ss = x.x*x.x + x.y*x.y + x.z*x.z + x.w*x.w;
    #pragma unroll
    for (int s = 1; s < 64; s <<= 1) ss += __shfl_xor(ss, s);
    float sc = 1.0f / fmaxf(sqrtf(ss), 1e-12f);
    __hip_fp8_e4m3 f0(x.x * sc), f1(x.y * sc), f2(x.z * sc), f3(x.w * sc);
    uchar4 o;
    o.x = *reinterpret_cast<unsigned char*>(&f0);
    o.y = *reinterpret_cast<unsigned char*>(&f1);
    o.z = *reinterpret_cast<unsigned char*>(&f2);
    o.w = *reinterpret_cast<unsigned char*>(&f3);
    int kp = (lane >> 4) * 64 + ((lane >> 1) & 3) * 16 + ((lane >> 3) & 1) * 8
           + (lane & 1) * 4;
    *reinterpret_cast<uchar4*>(e + (size_t)row * DIM + kp) = o;

    if (lane == 0) {
        u[row] = ent / 4.04305127f;
        atomicAdd(&task_count[tasks[row]], 1);
        scls[wave] = cls;
    }
    __syncthreads();
    if (threadIdx.x == 0) cls_part[blockIdx.x] = scls[0] + scls[1] + scls[2] + scls[3];
}

// ---- kernel 2 (REAL): full sim matrix, col-reduce, zero atomics (R10 unchanged) ----
__global__ __launch_bounds__(512, 2) void k_negA_full(
        const unsigned char* __restrict__ E, const int* __restrict__ tasks,
        float* __restrict__ partial) {
    __shared__ unsigned char Asm[128 * 256];
    __shared__ unsigned char ts[128];
    __shared__ float scr[3][256];

    int bm, bn; decode_block(bm, bn);
    int m0 = bm * 128, n0 = bn * 256;
    bool hasdiag = (bn == (bm >> 1));

    int tid = threadIdx.x;
    int w = tid >> 6, lane = tid & 63;
    int h = w >> 2, cg = w & 3;
    int g = lane >> 4, lr = lane & 15;
    int cbase = n0 + cg * 64;

    lgx2 bfr[4][4];
    #pragma unroll
    for (int f = 0; f < 4; ++f)
        #pragma unroll
        for (int t = 0; t < 4; ++t)
            bfr[f][t] = *reinterpret_cast<const lgx2*>(
                E + (size_t)(cbase + f * 16 + lr) * DIM + t * 64 + g * 16);

    #pragma unroll
    for (int it = 0; it < 4; ++it) {
        int flat = it * 512 + tid;
        int row = flat >> 4, kb = flat & 15;
        int kbs = kb ^ (row & 7);
        gload_lds16(E + (size_t)(m0 + row) * DIM + kbs * 16,
                    Asm + (size_t)(it * 512 + w * 64) * 16);
    }
    if (tid < 128) ts[tid] = (unsigned char)tasks[m0 + tid];
    __syncthreads();

    f32x4 acc[4][4] = {};
    #pragma unroll
    for (int t = 0; t < 4; ++t) {
        lgx2 a[4];
        #pragma unroll
        for (int m = 0; m < 4; ++m)
            a[m] = *reinterpret_cast<const lgx2*>(
                Asm + (size_t)(h * 64 + m * 16 + lr) * 256
                    + (((t * 4 + g) ^ (lr & 7)) * 16));
        #pragma unroll
        for (int m = 0; m < 4; ++m)
            #pragma unroll
            for (int f = 0; f < 4; ++f) {
                acc[m][f] = __builtin_amdgcn_mfma_f32_16x16x32_fp8_fp8(
                    a[m][0], bfr[f][t][0], acc[m][f], 0, 0, 0);
                acc[m][f] = __builtin_amdgcn_mfma_f32_16x16x32_fp8_fp8(
                    a[m][1], bfr[f][t][1], acc[m][f], 0, 0, 0);
            }
    }

    int ctb[4];
    #pragma unroll
    for (int f = 0; f < 4; ++f) ctb[f] = tasks[cbase + f * 16 + lr];
    float T[4] = {}, P[4] = {}, S[4] = {};
    #pragma unroll
    for (int m = 0; m < 4; ++m) {
        unsigned rt4 = *reinterpret_cast<const unsigned*>(&ts[h * 64 + m * 16 + g * 4]);
        #pragma unroll
        for (int r = 0; r < 4; ++r) {
            int rt = (rt4 >> (8 * r)) & 255;
            #pragma unroll
            for (int f = 0; f < 4; ++f) {
                float sv = acc[m][f][r] * INV_T;
                float ev = __expf(sv);
                bool keep = true;
                if (hasdiag)
                    keep = (m0 + h * 64 + m * 16 + g * 4 + r) != (cbase + f * 16 + lr);
                bool eq = (rt == ctb[f]) && keep;
                T[f] += keep ? ev : 0.0f;
                P[f] += eq ? ev : 0.0f;
                S[f] += eq ? sv : 0.0f;
            }
        }
    }
    #pragma unroll
    for (int f = 0; f < 4; ++f) {
        T[f] += __shfl_xor(T[f], 16); T[f] += __shfl_xor(T[f], 32);
        P[f] += __shfl_xor(P[f], 16); P[f] += __shfl_xor(P[f], 32);
        S[f] += __shfl_xor(S[f], 16); S[f] += __shfl_xor(S[f], 32);
    }
    if (h == 1 && g == 0) {
        #pragma unroll
        for (int f = 0; f < 4; ++f) {
            int c = cg * 64 + f * 16 + lr;
            scr[0][c] = T[f]; scr[1][c] = P[f]; scr[2][c] = S[f];
        }
    }
    __syncthreads();
    if (h == 0 && g == 0) {
        #pragma unroll
        for (int f = 0; f < 4; ++f) {
            int c = cg * 64 + f * 16 + lr;
            size_t sl = (size_t)bm * BSZ + n0 + c;
            partial[sl]                         = T[f] + scr[0][c];
            partial[(size_t)GBM * BSZ + sl]     = P[f] + scr[1][c];
            partial[(size_t)2 * GBM * BSZ + sl] = S[f] + scr[2][c];
        }
    }
}

// ---- PROBE B: identical GEMM, epilogue stripped (raw acc sums) ---------------------
__global__ __launch_bounds__(512, 2) void k_negB_noepi(
        const unsigned char* __restrict__ E, const int* __restrict__ tasks,
        float* __restrict__ dummy) {
    __shared__ unsigned char Asm[128 * 256];
    int bm, bn; decode_block(bm, bn);
    int m0 = bm * 128, n0 = bn * 256;
    int tid = threadIdx.x;
    int w = tid >> 6, lane = tid & 63;
    int h = w >> 2, cg = w & 3;
    int g = lane >> 4, lr = lane & 15;
    int cbase = n0 + cg * 64;

    lgx2 bfr[4][4];
    #pragma unroll
    for (int f = 0; f < 4; ++f)
        #pragma unroll
        for (int t = 0; t < 4; ++t)
            bfr[f][t] = *reinterpret_cast<const lgx2*>(
                E + (size_t)(cbase + f * 16 + lr) * DIM + t * 64 + g * 16);
    #pragma unroll
    for (int it = 0; it < 4; ++it) {
        int flat = it * 512 + tid;
        int row = flat >> 4, kb = flat & 15;
        int kbs = kb ^ (row & 7);
        gload_lds16(E + (size_t)(m0 + row) * DIM + kbs * 16,
                    Asm + (size_t)(it * 512 + w * 64) * 16);
    }
    __syncthreads();

    f32x4 acc[4][4] = {};
    #pragma unroll
    for (int t = 0; t < 4; ++t) {
        lgx2 a[4];
        #pragma unroll
        for (int m = 0; m < 4; ++m)
            a[m] = *reinterpret_cast<const lgx2*>(
                Asm + (size_t)(h * 64 + m * 16 + lr) * 256
                    + (((t * 4 + g) ^ (lr & 7)) * 16));
        #pragma unroll
        for (int m = 0; m < 4; ++m)
            #pragma unroll
            for (int f = 0; f < 4; ++f) {
                acc[m][f] = __builtin_amdgcn_mfma_f32_16x16x32_fp8_fp8(
                    a[m][0], bfr[f][t][0], acc[m][f], 0, 0, 0);
                acc[m][f] = __builtin_amdgcn_mfma_f32_16x16x32_fp8_fp8(
                    a[m][1], bfr[f][t][1], acc[m][f], 0, 0, 0);
            }
    }
    float s = 0.0f;
    #pragma unroll
    for (int m = 0; m < 4; ++m)
        #pragma unroll
        for (int f = 0; f < 4; ++f)
            #pragma unroll
            for (int r = 0; r < 4; ++r) s += acc[m][f][r];
    dummy[(size_t)blockIdx.x * 512 + tid] = s;     // keeps everything live
}

// ---- PROBE C: identical memory traffic (stage + B loads + ds_reads), NO MFMA -------
__global__ __launch_bounds__(512, 2) void k_negC_nomfma(
        const unsigned char* __restrict__ E, const int* __restrict__ tasks,
        float* __restrict__ dummy) {
    __shared__ unsigned char Asm[128 * 256];
    int bm, bn; decode_block(bm, bn);
    int m0 = bm * 128, n0 = bn * 256;
    int tid = threadIdx.x;
    int w = tid >> 6, lane = tid & 63;
    int h = w >> 2, cg = w & 3;
    int g = lane >> 4, lr = lane & 15;
    int cbase = n0 + cg * 64;

    lgx2 bfr[4][4];
    #pragma unroll
    for (int f = 0; f < 4; ++f)
        #pragma unroll
        for (int t = 0; t < 4; ++t)
            bfr[f][t] = *reinterpret_cast<const lgx2*>(
                E + (size_t)(cbase + f * 16 + lr) * DIM + t * 64 + g * 16);
    #pragma unroll
    for (int it = 0; it < 4; ++it) {
        int flat = it * 512 + tid;
        int row = flat >> 4, kb = flat & 15;
        int kbs = kb ^ (row & 7);
        gload_lds16(E + (size_t)(m0 + row) * DIM + kbs * 16,
                    Asm + (size_t)(it * 512 + w * 64) * 16);
    }
    __syncthreads();

    float s = 0.0f;
    #pragma unroll
    for (int t = 0; t < 4; ++t) {
        #pragma unroll
        for (int m = 0; m < 4; ++m) {
            lgx2 a = *reinterpret_cast<const lgx2*>(
                Asm + (size_t)(h * 64 + m * 16 + lr) * 256
                    + (((t * 4 + g) ^ (lr & 7)) * 16));
            float4 af = *reinterpret_cast<float4*>(&a);
            s += af.x + af.y + af.z + af.w;
        }
        #pragma unroll
        for (int f = 0; f < 4; ++f) {
            float4 bf2 = *reinterpret_cast<float4*>(&bfr[f][t]);
            s += bf2.x + bf2.y + bf2.z + bf2.w;
        }
    }
    dummy[(size_t)blockIdx.x * 512 + tid] = s;
}

// ---- PROBE D: full kernel with JIT B loads (live-set ~130 vs ~190) -----------------
__global__ __launch_bounds__(512, 2) void k_negD_jitb(
        const unsigned char* __restrict__ E, const int* __restrict__ tasks,
        float* __restrict__ dummy) {
    __shared__ unsigned char Asm[128 * 256];
    __shared__ unsigned char ts[128];
    __shared__ float scr[3][256];

    int bm, bn; decode_block(bm, bn);
    int m0 = bm * 128, n0 = bn * 256;
    bool hasdiag = (bn == (bm >> 1));
    int tid = threadIdx.x;
    int w = tid >> 6, lane = tid & 63;
    int h = w >> 2, cg = w & 3;
    int g = lane >> 4, lr = lane & 15;
    int cbase = n0 + cg * 64;
    const unsigned char* bp = E + (size_t)(cbase + lr) * DIM + g * 16;

    lgx2 bc[4];
    #pragma unroll
    for (int f = 0; f < 4; ++f)
        bc[f] = *reinterpret_cast<const lgx2*>(bp + (size_t)f * 16 * DIM);

    #pragma unroll
    for (int it = 0; it < 4; ++it) {
        int flat = it * 512 + tid;
        int row = flat >> 4, kb = flat & 15;
        int kbs = kb ^ (row & 7);
        gload_lds16(E + (size_t)(m0 + row) * DIM + kbs * 16,
                    Asm + (size_t)(it * 512 + w * 64) * 16);
    }
    if (tid < 128) ts[tid] = (unsigned char)tasks[m0 + tid];
    __syncthreads();

    f32x4 acc[4][4] = {};
    #pragma unroll 1
    for (int t = 0; t < 4; ++t) {
        lgx2 bn_[4];
        if (t < 3) {
            #pragma unroll
            for (int f = 0; f < 4; ++f)
                bn_[f] = *reinterpret_cast<const lgx2*>(
                    bp + (size_t)f * 16 * DIM + (t + 1) * 64);
        }
        lgx2 a[4];
        #pragma unroll
        for (int m = 0; m < 4; ++m)
            a[m] = *reinterpret_cast<const lgx2*>(
                Asm + (size_t)(h * 64 + m * 16 + lr) * 256
                    + (((t * 4 + g) ^ (lr & 7)) * 16));
        #pragma unroll
        for (int m = 0; m < 4; ++m)
            #pragma unroll
            for (int f = 0; f < 4; ++f) {
                acc[m][f] = __builtin_amdgcn_mfma_f32_16x16x32_fp8_fp8(
                    a[m][0], bc[f][0], acc[m][f], 0, 0, 0);
                acc[m][f] = __builtin_amdgcn_mfma_f32_16x16x32_fp8_fp8(
                    a[m][1], bc[f][1], acc[m][f], 0, 0, 0);
            }
        if (t < 3) {
            #pragma unroll
            for (int f = 0; f < 4; ++f) bc[f] = bn_[f];
        }
    }

    int ctb[4];
    #pragma unroll
    for (int f = 0; f < 4; ++f) ctb[f] = tasks[cbase + f * 16 + lr];
    float T[4] = {}, P[4] = {}, S[4] = {};
    #pragma unroll
    for (int m = 0; m < 4; ++m) {
        unsigned rt4 = *reinterpret_cast<const unsigned*>(&ts[h * 64 + m * 16 + g * 4]);
        #pragma unroll
        for (int r = 0; r < 4; ++r) {
            int rt = (rt4 >> (8 * r)) & 255;
            #pragma unroll
            for (int f = 0; f < 4; ++f) {
                float sv = acc[m][f][r] * INV_T;
                float ev = __expf(sv);
                bool keep = true;
                if (hasdiag)
                    keep = (m0 + h * 64 + m * 16 + g * 4 + r) != (cbase + f * 16 + lr);
                bool eq = (rt == ctb[f]) && keep;
                T[f] += keep ? ev : 0.0f;
                P[f] += eq ? ev : 0.0f;
                S[f] += eq ? sv : 0.0f;
            }
        }
    }
    #pragma unroll
    for (int f = 0; f < 4; ++f) {
        T[f] += __shfl_xor(T[f], 16); T[f] += __shfl_xor(T[f], 32);
        P[f] += __shfl_xor(P[f], 16); P[f] += __shfl_xor(P[f], 32);
        S[f] += __shfl_xor(S[f], 16); S[f] += __shfl_xor(S[f], 32);
    }
    if (h == 1 && g == 0) {
        #pragma unroll
        for (int f = 0; f < 4; ++f) {
            int c = cg * 64 + f * 16 + lr;
            scr[0][c] = T[f]; scr[1][c] = P[f]; scr[2][c] = S[f];
        }
    }
    __syncthreads();
    if (h == 0 && g == 0) {
        #pragma unroll
        for (int f = 0; f < 4; ++f) {
            int c = cg * 64 + f * 16 + lr;
            size_t sl = (size_t)bm * BSZ + n0 + c;
            dummy[sl]                         = T[f] + scr[0][c];
            dummy[(size_t)GBM * BSZ + sl]     = P[f] + scr[1][c];
            dummy[(size_t)2 * GBM * BSZ + sl] = S[f] + scr[2][c];
        }
    }
}

// ---- kernel 3: per-col finalize + ticket-fused combine (unchanged) -----------------
__global__ __launch_bounds__(256) void k_finalize(
        const int* __restrict__ tasks, const int* __restrict__ task_count,
        const float* __restrict__ partial, const float* __restrict__ u,
        const float* __restrict__ cls_part, float* __restrict__ contr_total,
        int* __restrict__ ticket, float* __restrict__ out) {
    __shared__ float sp[4];
    __shared__ int lastflag;
    int tid = threadIdx.x, wave = tid >> 6, lane = tid & 63;
    int j = blockIdx.x * 256 + tid;
    const float* pT = partial;
    const float* pP = partial + (size_t)GBM * BSZ;
    const float* pS = partial + (size_t)2 * GBM * BSZ;
    float T = 0.0f, P = 0.0f, S = 0.0f;
    #pragma unroll 8
    for (int bm = 0; bm < GBM; ++bm) {
        T += pT[(size_t)bm * BSZ + j];
        P += pP[(size_t)bm * BSZ + j];
        S += pS[(size_t)bm * BSZ + j];
    }
    float v = 0.0f;
    int c = task_count[tasks[j]];
    if (c >= 2 && c < BSZ) {
        float C = (T - P) + 1e-8f;
        v = u[j] * ((float)(c - 1) * logf(C) + P / C - S);
    }
    #pragma unroll
    for (int s = 1; s < 64; s <<= 1) v += __shfl_xor(v, s);
    if (lane == 0) sp[wave] = v;
    __syncthreads();
    if (tid == 0) {
        atomicAdd(contr_total, sp[0] + sp[1] + sp[2] + sp[3]);
        __threadfence();
        lastflag = (atomicAdd(ticket, 1) == FIN_GRID - 1);
    }
    __syncthreads();
    if (lastflag) {
        __threadfence();
        float c1 = 0.0f;
        for (int q = tid; q < BSZ / 4; q += 256) c1 += cls_part[q];
        long long cn = 0;
        if (tid < NTASK) {
            int cc = task_count[tid];
            if (cc >= 2 && cc < BSZ) cn = (long long)cc * (cc - 1);
        }
        #pragma unroll
        for (int s = 1; s < 64; s <<= 1) { c1 += __shfl_xor(c1, s); cn += __shfl_xor(cn, s); }
        __shared__ float scf[4]; __shared__ long long snf[4];
        if (lane == 0) { scf[wave] = c1; snf[wave] = cn; }
        __syncthreads();
        if (tid == 0) {
            float cls = (scf[0] + scf[1] + scf[2] + scf[3]) / (float)BSZ;
            long long cnt = snf[0] + snf[1] + snf[2] + snf[3];
            float con = __hip_atomic_load(contr_total, __ATOMIC_ACQUIRE,
                                          __HIP_MEMORY_SCOPE_AGENT);
            out[0] = 0.7f * cls + 0.3f * (cnt > 0 ? con / (float)cnt : 0.0f);
        }
    }
}

extern "C" void kernel_launch(void* const* d_in, const int* in_sizes, int n_in,
                              void* d_out, int out_size, void* d_ws, size_t ws_size,
                              hipStream_t stream) {
    const float* logits = (const float*)d_in[0];
    const float* emb    = (const float*)d_in[1];
    const int*   labels = (const int*)d_in[2];
    const int*   tasks  = (const int*)d_in[3];
    float* out = (float*)d_out;

    char* ws = (char*)d_ws;
    float* contr_total = (float*)ws;
    int*   ticket      = (int*)ws + 1;
    int*   task_count  = (int*)ws + 64;
    float* u           = (float*)ws + 512;
    float* cls_part    = u + BSZ;
    float* partial     = cls_part + 2048;
    unsigned char* e   = (unsigned char*)(partial + (size_t)3 * GBM * BSZ);
    float* dummy       = (float*)(e + (size_t)BSZ * DIM);   // 6 MB probe scratch

    hipMemsetAsync(ws, 0, 512 * 4, stream);

    k_prep     <<<BSZ / 4,   256, 0, stream>>>(logits, emb, labels, tasks, u, cls_part,
                                               task_count, e);
    k_negA_full<<<GBM * GBN, 512, 0, stream>>>(e, tasks, partial);
    // ---- diagnostic probes (write only to dummy; do not affect the result) ----
    k_negB_noepi <<<GBM * GBN, 512, 0, stream>>>(e, tasks, dummy);
    k_negC_nomfma<<<GBM * GBN, 512, 0, stream>>>(e, tasks, dummy);
    k_negD_jitb  <<<GBM * GBN, 512, 0, stream>>>(e, tasks, dummy);
    // ----------------------------------------------------------------------------
    k_finalize <<<FIN_GRID,  256, 0, stream>>>(tasks, task_count, partial, u, cls_part,
                                               contr_total, ticket, out);
}

// Round 12
// 106.912 us; speedup vs baseline: 2.3145x; 2.3145x over previous
//
#include <hip/hip_runtime.h>
#include <hip/hip_fp8.h>
#include <math.h>

#define BSZ   8192
#define NCLS  57
#define DIM   256
#define NTASK 57
#define INV_T (1.0f/0.07f)
#define GBM   64                 // row tiles (128 rows each)
#define GBN   32                 // col tiles (256 cols each)
#define FIN_GRID 32

typedef float f32x4 __attribute__((ext_vector_type(4)));
typedef long  lgx2  __attribute__((ext_vector_type(2)));

// async global->LDS, 16B per lane; l must be wave-uniform base (HW adds lane*16)
__device__ __forceinline__ void gload_lds16(const void* g, void* l) {
    __builtin_amdgcn_global_load_lds(
        (const __attribute__((address_space(1))) unsigned int*)g,
        (__attribute__((address_space(3))) unsigned int*)l, 16, 0, 0);
}

// ---- kernel 1: fused logits stats + normalize->fp8 (K-interleaved) -----------------
// fp8 K-layout: k' = (ks>>1)*64 + g*16 + (ks&1)*8 + b for original k = ks*32+g*8+b:
// makes A/B fragment reads pure b128 (verified R9/R10).
__global__ __launch_bounds__(256) void k_prep(
        const float* __restrict__ logits, const float* __restrict__ emb,
        const int* __restrict__ labels, const int* __restrict__ tasks,
        float* __restrict__ u, float* __restrict__ cls_part,
        int* __restrict__ task_count, unsigned char* __restrict__ e) {
    __shared__ float scls[4];
    int wave = threadIdx.x >> 6;
    int lane = threadIdx.x & 63;
    int row  = blockIdx.x * 4 + wave;

    float v = (lane < NCLS) ? logits[row * NCLS + lane] : -3.0e38f;
    float m = v;
    #pragma unroll
    for (int s = 1; s < 64; s <<= 1) m = fmaxf(m, __shfl_xor(m, s));
    float ex = (lane < NCLS) ? __expf(v - m) : 0.0f;
    float se = ex;
    #pragma unroll
    for (int s = 1; s < 64; s <<= 1) se += __shfl_xor(se, s);
    float lse = m + logf(se);
    float p = ex / se;
    float term = (lane < NCLS) ? p * logf(p + 1e-8f) : 0.0f;
    float ent = term;
    #pragma unroll
    for (int s = 1; s < 64; s <<= 1) ent += __shfl_xor(ent, s);
    ent = -ent;
    int lab = labels[row];
    float vl = __shfl(v, lab);
    float cls = lse - vl;

    const float4* src = reinterpret_cast<const float4*>(emb + (size_t)row * DIM);
    float4 x = src[lane];
    float ss = x.x*x.x + x.y*x.y + x.z*x.z + x.w*x.w;
    #pragma unroll
    for (int s = 1; s < 64; s <<= 1) ss += __shfl_xor(ss, s);
    float sc = 1.0f / fmaxf(sqrtf(ss), 1e-12f);
    __hip_fp8_e4m3 f0(x.x * sc), f1(x.y * sc), f2(x.z * sc), f3(x.w * sc);
    uchar4 o;
    o.x = *reinterpret_cast<unsigned char*>(&f0);
    o.y = *reinterpret_cast<unsigned char*>(&f1);
    o.z = *reinterpret_cast<unsigned char*>(&f2);
    o.w = *reinterpret_cast<unsigned char*>(&f3);
    int kp = (lane >> 4) * 64 + ((lane >> 1) & 3) * 16 + ((lane >> 3) & 1) * 8
           + (lane & 1) * 4;
    *reinterpret_cast<uchar4*>(e + (size_t)row * DIM + kp) = o;

    if (lane == 0) {
        u[row] = ent / 4.04305127f;      // log(57)
        atomicAdd(&task_count[tasks[row]], 1);
        scls[wave] = cls;
    }
    __syncthreads();
    if (threadIdx.x == 0) cls_part[blockIdx.x] = scls[0] + scls[1] + scls[2] + scls[3];
}

// ---- kernel 2: full sim matrix, col-reduce, zero atomics, JIT B (R11 probe D) ------
// R11 ablation: the up-front 32-VGPR B block pushed the unified live set to ~140 regs
// -> 1 block/CU (the 5-round 70us wall). JIT B (8 regs rolling, rolled K-loop) fits
// <=128 -> 2 blocks/CU. Epilogue cost confirmed non-wall by the same ablation.
// Per col j, block accumulates T=sum e^s (excl diag), P=sum_same e^s, S=sum_same s
// over its 128 rows -> partial[q][bm][j], unique writer (no atomics).
__global__ __launch_bounds__(512, 2) void k_negsum(
        const unsigned char* __restrict__ E, const int* __restrict__ tasks,
        float* __restrict__ partial) {
    __shared__ unsigned char Asm[128 * 256];   // 32 KB
    __shared__ unsigned char ts[128];
    __shared__ float scr[3][256];

    // XCD swizzle (2048 % 8 == 0 -> bijective); consecutive swz share bm (A L2 reuse)
    int b = (blockIdx.x & 7) * (2048 / 8) + (blockIdx.x >> 3);
    int bm = b >> 5, bn = b & 31;
    int m0 = bm * 128, n0 = bn * 256;
    bool hasdiag = (bn == (bm >> 1));

    int tid = threadIdx.x;
    int w = tid >> 6, lane = tid & 63;
    int h = w >> 2, cg = w & 3;
    int g = lane >> 4, lr = lane & 15;
    int cbase = n0 + cg * 64;
    const unsigned char* bp = E + (size_t)(cbase + lr) * DIM + g * 16;

    lgx2 bc[4];
    #pragma unroll
    for (int f = 0; f < 4; ++f)
        bc[f] = *reinterpret_cast<const lgx2*>(bp + (size_t)f * 16 * DIM);

    #pragma unroll
    for (int it = 0; it < 4; ++it) {
        int flat = it * 512 + tid;       // 16B chunk 0..2047
        int row = flat >> 4, kb = flat & 15;
        int kbs = kb ^ (row & 7);        // source-side chunk XOR (read applies same)
        gload_lds16(E + (size_t)(m0 + row) * DIM + kbs * 16,
                    Asm + (size_t)(it * 512 + w * 64) * 16);
    }
    if (tid < 128) ts[tid] = (unsigned char)tasks[m0 + tid];
    __syncthreads();                     // the only pre-epilogue barrier

    f32x4 acc[4][4] = {};
    #pragma unroll 1
    for (int t = 0; t < 4; ++t) {
        lgx2 bn_[4];
        if (t < 3) {
            #pragma unroll
            for (int f = 0; f < 4; ++f)
                bn_[f] = *reinterpret_cast<const lgx2*>(
                    bp + (size_t)f * 16 * DIM + (t + 1) * 64);
        }
        lgx2 a[4];
        #pragma unroll
        for (int m = 0; m < 4; ++m)
            a[m] = *reinterpret_cast<const lgx2*>(
                Asm + (size_t)(h * 64 + m * 16 + lr) * 256
                    + (((t * 4 + g) ^ (lr & 7)) * 16));
        #pragma unroll
        for (int m = 0; m < 4; ++m)
            #pragma unroll
            for (int f = 0; f < 4; ++f) {
                acc[m][f] = __builtin_amdgcn_mfma_f32_16x16x32_fp8_fp8(
                    a[m][0], bc[f][0], acc[m][f], 0, 0, 0);
                acc[m][f] = __builtin_amdgcn_mfma_f32_16x16x32_fp8_fp8(
                    a[m][1], bc[f][1], acc[m][f], 0, 0, 0);
            }
        if (t < 3) {
            #pragma unroll
            for (int f = 0; f < 4; ++f) bc[f] = bn_[f];
        }
    }

    int ctb[4];
    #pragma unroll
    for (int f = 0; f < 4; ++f) ctb[f] = tasks[cbase + f * 16 + lr];
    float T[4] = {}, P[4] = {}, S[4] = {};
    #pragma unroll
    for (int m = 0; m < 4; ++m) {
        unsigned rt4 = *reinterpret_cast<const unsigned*>(&ts[h * 64 + m * 16 + g * 4]);
        #pragma unroll
        for (int r = 0; r < 4; ++r) {
            int rt = (rt4 >> (8 * r)) & 255;
            #pragma unroll
            for (int f = 0; f < 4; ++f) {
                float sv = acc[m][f][r] * INV_T;
                float ev = __expf(sv);
                bool keep = true;
                if (hasdiag)
                    keep = (m0 + h * 64 + m * 16 + g * 4 + r) != (cbase + f * 16 + lr);
                bool eq = (rt == ctb[f]) && keep;
                T[f] += keep ? ev : 0.0f;
                P[f] += eq ? ev : 0.0f;
                S[f] += eq ? sv : 0.0f;
            }
        }
    }
    #pragma unroll
    for (int f = 0; f < 4; ++f) {        // cross-g butterfly: 2 shfl per quantity
        T[f] += __shfl_xor(T[f], 16); T[f] += __shfl_xor(T[f], 32);
        P[f] += __shfl_xor(P[f], 16); P[f] += __shfl_xor(P[f], 32);
        S[f] += __shfl_xor(S[f], 16); S[f] += __shfl_xor(S[f], 32);
    }
    if (h == 1 && g == 0) {
        #pragma unroll
        for (int f = 0; f < 4; ++f) {
            int c = cg * 64 + f * 16 + lr;
            scr[0][c] = T[f]; scr[1][c] = P[f]; scr[2][c] = S[f];
        }
    }
    __syncthreads();
    if (h == 0 && g == 0) {
        #pragma unroll
        for (int f = 0; f < 4; ++f) {
            int c = cg * 64 + f * 16 + lr;
            size_t sl = (size_t)bm * BSZ + n0 + c;
            partial[sl]                         = T[f] + scr[0][c];
            partial[(size_t)GBM * BSZ + sl]     = P[f] + scr[1][c];
            partial[(size_t)2 * GBM * BSZ + sl] = S[f] + scr[2][c];
        }
    }
}

// ---- kernel 3: per-col finalize + ticket-fused combine -----------------------------
// neg_j = T_j - P_j; contr_j = u_j*((c-1)*log(C) + P_j/C - S_j), C = neg_j + 1e-8
// (first-order expansion validated R9/R10, absmax 0).
__global__ __launch_bounds__(256) void k_finalize(
        const int* __restrict__ tasks, const int* __restrict__ task_count,
        const float* __restrict__ partial, const float* __restrict__ u,
        const float* __restrict__ cls_part, float* __restrict__ contr_total,
        int* __restrict__ ticket, float* __restrict__ out) {
    __shared__ float sp[4];
    __shared__ int lastflag;
    int tid = threadIdx.x, wave = tid >> 6, lane = tid & 63;
    int j = blockIdx.x * 256 + tid;
    const float* pT = partial;
    const float* pP = partial + (size_t)GBM * BSZ;
    const float* pS = partial + (size_t)2 * GBM * BSZ;
    float T = 0.0f, P = 0.0f, S = 0.0f;
    #pragma unroll 8
    for (int bm = 0; bm < GBM; ++bm) {
        T += pT[(size_t)bm * BSZ + j];
        P += pP[(size_t)bm * BSZ + j];
        S += pS[(size_t)bm * BSZ + j];
    }
    float v = 0.0f;
    int c = task_count[tasks[j]];
    if (c >= 2 && c < BSZ) {
        float C = (T - P) + 1e-8f;
        v = u[j] * ((float)(c - 1) * logf(C) + P / C - S);
    }
    #pragma unroll
    for (int s = 1; s < 64; s <<= 1) v += __shfl_xor(v, s);
    if (lane == 0) sp[wave] = v;
    __syncthreads();
    if (tid == 0) {
        atomicAdd(contr_total, sp[0] + sp[1] + sp[2] + sp[3]);
        __threadfence();
        lastflag = (atomicAdd(ticket, 1) == FIN_GRID - 1);
    }
    __syncthreads();
    if (lastflag) {                      // last block: all contributions landed
        __threadfence();
        float c1 = 0.0f;
        for (int q = tid; q < BSZ / 4; q += 256) c1 += cls_part[q];
        long long cn = 0;
        if (tid < NTASK) {
            int cc = task_count[tid];
            if (cc >= 2 && cc < BSZ) cn = (long long)cc * (cc - 1);
        }
        #pragma unroll
        for (int s = 1; s < 64; s <<= 1) { c1 += __shfl_xor(c1, s); cn += __shfl_xor(cn, s); }
        __shared__ float scf[4]; __shared__ long long snf[4];
        if (lane == 0) { scf[wave] = c1; snf[wave] = cn; }
        __syncthreads();
        if (tid == 0) {
            float cls = (scf[0] + scf[1] + scf[2] + scf[3]) / (float)BSZ;
            long long cnt = snf[0] + snf[1] + snf[2] + snf[3];
            float con = __hip_atomic_load(contr_total, __ATOMIC_ACQUIRE,
                                          __HIP_MEMORY_SCOPE_AGENT);
            out[0] = 0.7f * cls + 0.3f * (cnt > 0 ? con / (float)cnt : 0.0f);
        }
    }
}

extern "C" void kernel_launch(void* const* d_in, const int* in_sizes, int n_in,
                              void* d_out, int out_size, void* d_ws, size_t ws_size,
                              hipStream_t stream) {
    const float* logits = (const float*)d_in[0];
    const float* emb    = (const float*)d_in[1];
    const int*   labels = (const int*)d_in[2];
    const int*   tasks  = (const int*)d_in[3];
    float* out = (float*)d_out;

    char* ws = (char*)d_ws;
    // layout (4B units):
    // header[512]: [0]=contr_total [1]=ticket [64..]=task_count
    // u[BSZ], cls_part[2048], partial[3*64*8192] (6 MB), E fp8[BSZ*DIM] (2 MB)
    float* contr_total = (float*)ws;
    int*   ticket      = (int*)ws + 1;
    int*   task_count  = (int*)ws + 64;
    float* u           = (float*)ws + 512;
    float* cls_part    = u + BSZ;
    float* partial     = cls_part + 2048;
    unsigned char* e   = (unsigned char*)(partial + (size_t)3 * GBM * BSZ);

    // zero header only (contr/ticket/task_count); partial has unique writers
    hipMemsetAsync(ws, 0, 512 * 4, stream);

    k_prep    <<<BSZ / 4,   256, 0, stream>>>(logits, emb, labels, tasks, u, cls_part,
                                              task_count, e);
    k_negsum  <<<GBM * GBN, 512, 0, stream>>>(e, tasks, partial);
    k_finalize<<<FIN_GRID,  256, 0, stream>>>(tasks, task_count, partial, u, cls_part,
                                              contr_total, ticket, out);
}

// Round 13
// 92.208 us; speedup vs baseline: 2.6836x; 1.1595x over previous
//
#include <hip/hip_runtime.h>
#include <hip/hip_fp8.h>
#include <math.h>

#define BSZ   8192
#define NCLS  57
#define DIM   256
#define NTASK 57
#define INV_T (1.0f/0.07f)
#define GBM   64                 // row tiles (128 rows each)
#define GBN   32                 // col tiles (256 cols each)
#define NTILE (GBM * GBN)        // 2048

typedef float f32x4 __attribute__((ext_vector_type(4)));
typedef long  lgx2  __attribute__((ext_vector_type(2)));

// async global->LDS, 16B per lane; l must be wave-uniform base (HW adds lane*16)
__device__ __forceinline__ void gload_lds16(const void* g, void* l) {
    __builtin_amdgcn_global_load_lds(
        (const __attribute__((address_space(1))) unsigned int*)g,
        (__attribute__((address_space(3))) unsigned int*)l, 16, 0, 0);
}

// ---- kernel 1: fused logits stats + normalize->fp8 (K-interleaved) + zero-init -----
// fp8 K-layout: k' = (ks>>1)*64 + g*16 + (ks&1)*8 + b for original k = ks*32+g*8+b:
// makes A/B fragment reads pure b128 (verified R9/R10). Zeros T/P/S rows + ticket
// (replaces the memset node); cls partials go to unique slots (no atomic).
__global__ __launch_bounds__(256) void k_prep(
        const float* __restrict__ logits, const float* __restrict__ emb,
        const int* __restrict__ labels, float* __restrict__ u,
        float* __restrict__ cls_part, unsigned char* __restrict__ e,
        float* __restrict__ Tg, int* __restrict__ ticket) {
    __shared__ float scls[4];
    int wave = threadIdx.x >> 6;
    int lane = threadIdx.x & 63;
    int row  = blockIdx.x * 4 + wave;

    float v = (lane < NCLS) ? logits[row * NCLS + lane] : -3.0e38f;
    float m = v;
    #pragma unroll
    for (int s = 1; s < 64; s <<= 1) m = fmaxf(m, __shfl_xor(m, s));
    float ex = (lane < NCLS) ? __expf(v - m) : 0.0f;
    float se = ex;
    #pragma unroll
    for (int s = 1; s < 64; s <<= 1) se += __shfl_xor(se, s);
    float lse = m + logf(se);
    float p = ex / se;
    float term = (lane < NCLS) ? p * logf(p + 1e-8f) : 0.0f;
    float ent = term;
    #pragma unroll
    for (int s = 1; s < 64; s <<= 1) ent += __shfl_xor(ent, s);
    ent = -ent;
    int lab = labels[row];
    float vl = __shfl(v, lab);
    float cls = lse - vl;

    const float4* src = reinterpret_cast<const float4*>(emb + (size_t)row * DIM);
    float4 x = src[lane];
    float ss = x.x*x.x + x.y*x.y + x.z*x.z + x.w*x.w;
    #pragma unroll
    for (int s = 1; s < 64; s <<= 1) ss += __shfl_xor(ss, s);
    float sc = 1.0f / fmaxf(sqrtf(ss), 1e-12f);
    __hip_fp8_e4m3 f0(x.x * sc), f1(x.y * sc), f2(x.z * sc), f3(x.w * sc);
    uchar4 o;
    o.x = *reinterpret_cast<unsigned char*>(&f0);
    o.y = *reinterpret_cast<unsigned char*>(&f1);
    o.z = *reinterpret_cast<unsigned char*>(&f2);
    o.w = *reinterpret_cast<unsigned char*>(&f3);
    int kp = (lane >> 4) * 64 + ((lane >> 1) & 3) * 16 + ((lane >> 3) & 1) * 8
           + (lane & 1) * 4;
    *reinterpret_cast<uchar4*>(e + (size_t)row * DIM + kp) = o;

    if (lane == 0) {
        u[row] = ent / 4.04305127f;      // log(57)
        Tg[row] = 0.0f;                  // zero T/P/S accumulators for k_negsum
        Tg[BSZ + row] = 0.0f;
        Tg[2 * BSZ + row] = 0.0f;
        scls[wave] = cls;
    }
    if (blockIdx.x == 0 && threadIdx.x == 0) *ticket = 0;
    __syncthreads();
    if (threadIdx.x == 0) cls_part[blockIdx.x] = scls[0] + scls[1] + scls[2] + scls[3];
}

// ---- epilogue accumulate, specialized on whether the tile contains the diagonal ----
template<bool HD>
__device__ __forceinline__ void epi_accum(
        const f32x4 (&acc)[4][4], const unsigned char* ts, const int* ctb,
        int m0, int cbase, int h, int g, int lr,
        float (&T)[4], float (&P)[4], float (&S)[4]) {
    #pragma unroll
    for (int m = 0; m < 4; ++m) {
        unsigned rt4 = *reinterpret_cast<const unsigned*>(&ts[h * 64 + m * 16 + g * 4]);
        #pragma unroll
        for (int r = 0; r < 4; ++r) {
            int rt = (rt4 >> (8 * r)) & 255;
            #pragma unroll
            for (int f = 0; f < 4; ++f) {
                float sv = acc[m][f][r] * INV_T;
                float ev = __expf(sv);
                bool keep = true;
                if (HD)
                    keep = (m0 + h * 64 + m * 16 + g * 4 + r) != (cbase + f * 16 + lr);
                bool eq = (rt == ctb[f]) && keep;
                T[f] += keep ? ev : 0.0f;
                P[f] += eq ? ev : 0.0f;
                S[f] += eq ? sv : 0.0f;
            }
        }
    }
}

// ---- kernel 2: full sim matrix + atomic T/P/S + ticket-fused finalize --------------
// GEMM core = R12 (JIT B regs, <=128 unified regs, 2 blocks/CU). Epilogue: each wave
// butterflies over g then g==0 lanes atomicAdd 64-row partials into T/P/S[col]
// (device-scope, coherent across XCDs; 3.1M adds @ ~65M/s — negligible). The LAST
// block (ticket) re-derives the task histogram in LDS and computes the entire final
// scalar locally: contr via first-order expansion (validated R9/R10), cls from
// cls_part slots, count from hist. Two graph nodes total.
__global__ __launch_bounds__(512, 2) void k_negsum(
        const unsigned char* __restrict__ E, const int* __restrict__ tasks,
        float* __restrict__ Tg, const float* __restrict__ u,
        const float* __restrict__ cls_part, int* __restrict__ ticket,
        float* __restrict__ out) {
    __shared__ unsigned char Asm[128 * 256];   // 32 KB
    __shared__ unsigned char ts[128];
    __shared__ int lastflag;
    __shared__ int hist[NTASK];
    __shared__ float red[8][2];
    __shared__ long long redn[8];

    // XCD swizzle (2048 % 8 == 0 -> bijective); consecutive swz share bm (A L2 reuse)
    int b = (blockIdx.x & 7) * (NTILE / 8) + (blockIdx.x >> 3);
    int bm = b >> 5, bn = b & 31;
    int m0 = bm * 128, n0 = bn * 256;
    bool hasdiag = (bn == (bm >> 1));

    int tid = threadIdx.x;
    int w = tid >> 6, lane = tid & 63;
    int h = w >> 2, cg = w & 3;
    int g = lane >> 4, lr = lane & 15;
    int cbase = n0 + cg * 64;
    const unsigned char* bp = E + (size_t)(cbase + lr) * DIM + g * 16;

    lgx2 bc[4];
    #pragma unroll
    for (int f = 0; f < 4; ++f)
        bc[f] = *reinterpret_cast<const lgx2*>(bp + (size_t)f * 16 * DIM);

    #pragma unroll
    for (int it = 0; it < 4; ++it) {
        int flat = it * 512 + tid;       // 16B chunk 0..2047
        int row = flat >> 4, kb = flat & 15;
        int kbs = kb ^ (row & 7);        // source-side chunk XOR (read applies same)
        gload_lds16(E + (size_t)(m0 + row) * DIM + kbs * 16,
                    Asm + (size_t)(it * 512 + w * 64) * 16);
    }
    if (tid < 128) ts[tid] = (unsigned char)tasks[m0 + tid];
    __syncthreads();                     // the only pre-epilogue barrier

    f32x4 acc[4][4] = {};
    #pragma unroll 1
    for (int t = 0; t < 4; ++t) {
        lgx2 bn_[4];
        if (t < 3) {
            #pragma unroll
            for (int f = 0; f < 4; ++f)
                bn_[f] = *reinterpret_cast<const lgx2*>(
                    bp + (size_t)f * 16 * DIM + (t + 1) * 64);
        }
        lgx2 a[4];
        #pragma unroll
        for (int m = 0; m < 4; ++m)
            a[m] = *reinterpret_cast<const lgx2*>(
                Asm + (size_t)(h * 64 + m * 16 + lr) * 256
                    + (((t * 4 + g) ^ (lr & 7)) * 16));
        #pragma unroll
        for (int m = 0; m < 4; ++m)
            #pragma unroll
            for (int f = 0; f < 4; ++f) {
                acc[m][f] = __builtin_amdgcn_mfma_f32_16x16x32_fp8_fp8(
                    a[m][0], bc[f][0], acc[m][f], 0, 0, 0);
                acc[m][f] = __builtin_amdgcn_mfma_f32_16x16x32_fp8_fp8(
                    a[m][1], bc[f][1], acc[m][f], 0, 0, 0);
            }
        if (t < 3) {
            #pragma unroll
            for (int f = 0; f < 4; ++f) bc[f] = bn_[f];
        }
    }

    int ctb[4];
    #pragma unroll
    for (int f = 0; f < 4; ++f) ctb[f] = tasks[cbase + f * 16 + lr];
    float T[4] = {}, P[4] = {}, S[4] = {};
    if (hasdiag) epi_accum<true >(acc, ts, ctb, m0, cbase, h, g, lr, T, P, S);
    else         epi_accum<false>(acc, ts, ctb, m0, cbase, h, g, lr, T, P, S);

    #pragma unroll
    for (int f = 0; f < 4; ++f) {        // cross-g butterfly: 2 shfl per quantity
        T[f] += __shfl_xor(T[f], 16); T[f] += __shfl_xor(T[f], 32);
        P[f] += __shfl_xor(P[f], 16); P[f] += __shfl_xor(P[f], 32);
        S[f] += __shfl_xor(S[f], 16); S[f] += __shfl_xor(S[f], 32);
    }
    if (g == 0) {                        // per-wave 64-row partials -> global atomics
        #pragma unroll
        for (int f = 0; f < 4; ++f) {
            int c = cbase + f * 16 + lr;
            atomicAdd(&Tg[c], T[f]);
            atomicAdd(&Tg[BSZ + c], P[f]);
            atomicAdd(&Tg[2 * BSZ + c], S[f]);
        }
    }

    // ---- ticket: last block computes the final scalar ----
    __syncthreads();                     // drains this block's atomics (waitcnt+bar)
    if (tid == 0) {
        __threadfence();
        lastflag = (atomicAdd(ticket, 1) == NTILE - 1);
    }
    __syncthreads();
    if (!lastflag) return;
    __threadfence();                     // acquire: all blocks' atomics visible

    if (tid < NTASK) hist[tid] = 0;
    __syncthreads();
    for (int i = tid; i < BSZ; i += 512) atomicAdd(&hist[tasks[i]], 1);
    __syncthreads();

    float v = 0.0f;
    for (int j = tid; j < BSZ; j += 512) {
        float Tj = __hip_atomic_load(&Tg[j], __ATOMIC_RELAXED, __HIP_MEMORY_SCOPE_AGENT);
        float Pj = __hip_atomic_load(&Tg[BSZ + j], __ATOMIC_RELAXED, __HIP_MEMORY_SCOPE_AGENT);
        float Sj = __hip_atomic_load(&Tg[2 * BSZ + j], __ATOMIC_RELAXED, __HIP_MEMORY_SCOPE_AGENT);
        int c = hist[tasks[j]];
        if (c >= 2 && c < BSZ) {
            float C = (Tj - Pj) + 1e-8f;
            v += u[j] * ((float)(c - 1) * logf(C) + Pj / C - Sj);
        }
    }
    float cl = 0.0f;
    for (int q = tid; q < BSZ / 4; q += 512) cl += cls_part[q];
    long long cn = 0;
    if (tid < NTASK) {
        int cc = hist[tid];
        if (cc >= 2 && cc < BSZ) cn = (long long)cc * (cc - 1);
    }
    #pragma unroll
    for (int s = 1; s < 64; s <<= 1) {
        v  += __shfl_xor(v, s);
        cl += __shfl_xor(cl, s);
        cn += __shfl_xor(cn, s);
    }
    if (lane == 0) { red[w][0] = v; red[w][1] = cl; redn[w] = cn; }
    __syncthreads();
    if (tid == 0) {
        float vt = 0.0f, ct = 0.0f; long long cnt = 0;
        #pragma unroll
        for (int q = 0; q < 8; ++q) { vt += red[q][0]; ct += red[q][1]; cnt += redn[q]; }
        out[0] = 0.7f * (ct / (float)BSZ)
               + 0.3f * (cnt > 0 ? vt / (float)cnt : 0.0f);
    }
}

extern "C" void kernel_launch(void* const* d_in, const int* in_sizes, int n_in,
                              void* d_out, int out_size, void* d_ws, size_t ws_size,
                              hipStream_t stream) {
    const float* logits = (const float*)d_in[0];
    const float* emb    = (const float*)d_in[1];
    const int*   labels = (const int*)d_in[2];
    const int*   tasks  = (const int*)d_in[3];
    float* out = (float*)d_out;

    char* ws = (char*)d_ws;
    // layout (4B units):
    // [0]=ticket  [64..]=Tg[3*BSZ] (T,P,S)  then u[BSZ], cls_part[2048], E fp8
    int*   ticket   = (int*)ws;
    float* Tg       = (float*)ws + 64;
    float* u        = Tg + 3 * BSZ;
    float* cls_part = u + BSZ;
    unsigned char* e = (unsigned char*)(cls_part + 2048);

    // 2 nodes; k_prep zero-inits ticket + T/P/S (no memset node)
    k_prep  <<<BSZ / 4, 256, 0, stream>>>(logits, emb, labels, u, cls_part, e,
                                          Tg, ticket);
    k_negsum<<<NTILE,   512, 0, stream>>>(e, tasks, Tg, u, cls_part, ticket, out);
}